// Round 2
// baseline (4503.857 us; speedup 1.0000x reference)
//
#include <hip/hip_runtime.h>

// GRNN (NRI) encoder, MI355X gfx950.
// B=8, N=16, T=64, D=4, H=256, E=240, BT=512, BR=1920.
// fp16 MFMA (f32 accum) GEMMs; BN fused into consumer staging; LSTM chunked.
// Workspace: ~214 MB.

typedef __attribute__((ext_vector_type(4))) float f32x4;
typedef __attribute__((ext_vector_type(8))) _Float16 f16x8;

#define DEVFN static __device__ __forceinline__

DEVFN float elu_f(float x)  { return x > 0.f ? x : __expf(x) - 1.f; }
DEVFN float sig_f(float x)  { return 1.f / (1.f + __expf(-x)); }
DEVFN float tanh_f(float x) { return 1.f - 2.f / (1.f + __expf(2.f * x)); }

#define M_ID  0   // A row r -> A0 row r
#define M_N2E 1   // r=(bt*240+e): seg0 A0[bt*16+sidx[e]], seg1 A0[bt*16+ridx[e]]
#define M_M4  2   // seg0/1 as N2E from A0, seg2 A1[r]
#define M_L0  3   // r=q: rr=q>>4,t=tc+(q&15): A0[(b*64+t)*240+e]  (bn4 stats)
#define M_LN  4   // A0[(r>>4)*64 + tc + (r&15)]

// ---------------------------------------------------------------------------
// Gather-GEMM: out[M,O] = epi(gatherA[M,K] @ W[O,K]^T + bias).
// All A segments are width 256, stride 256. K = NSEG*256.
// BN scale/shift (stats[512+c], stats[768+c]) applied on A load when HAS_ST.
// ---------------------------------------------------------------------------
template<int MODE, bool DOELU>
__global__ __launch_bounds__(256) void gemmg(
    const _Float16* __restrict__ A0, const _Float16* __restrict__ A1,
    const float* __restrict__ st0, const float* __restrict__ st1,
    const int* __restrict__ sidx, const int* __restrict__ ridx,
    const _Float16* __restrict__ W, const float* __restrict__ bias,
    _Float16* __restrict__ out, int M, int O, int tc)
{
    constexpr int NSEG = (MODE == M_M4) ? 3 : ((MODE == M_N2E) ? 2 : 1);
    constexpr bool HAS_ST = (MODE == M_N2E) || (MODE == M_M4) || (MODE == M_L0);
    const int K = NSEG * 256;

    __shared__ _Float16 As[128][40];
    __shared__ _Float16 Ws[128][40];

    const int tid  = threadIdx.x;
    const int lane = tid & 63;
    const int wv   = tid >> 6;
    const int wr   = wv >> 1, wc = wv & 1;
    const int lr   = lane & 15, kg = lane >> 4;
    const int m0   = blockIdx.x * 128;
    const int o0   = blockIdx.y * 128;
    const int srow = tid >> 1;
    const int scol = (tid & 1) * 16;

    const _Float16* ab[3] = {nullptr, nullptr, nullptr};
    const float*   stp[3] = {nullptr, nullptr, nullptr};
    {
        int r = m0 + srow;
        if constexpr (MODE == M_ID) {
            ab[0] = A0 + (size_t)r * 256;
        } else if constexpr (MODE == M_N2E) {
            int bt = r / 240, e = r - bt * 240;
            ab[0] = A0 + (size_t)(bt * 16 + sidx[e]) * 256;
            ab[1] = A0 + (size_t)(bt * 16 + ridx[e]) * 256;
            stp[0] = st0; stp[1] = st0;
        } else if constexpr (MODE == M_M4) {
            int bt = r / 240, e = r - bt * 240;
            ab[0] = A0 + (size_t)(bt * 16 + sidx[e]) * 256;
            ab[1] = A0 + (size_t)(bt * 16 + ridx[e]) * 256;
            ab[2] = A1 + (size_t)r * 256;
            stp[0] = st0; stp[1] = st0; stp[2] = st1;
        } else if constexpr (MODE == M_L0) {
            int rr = r >> 4, t = tc + (r & 15);
            int b = rr / 240, e = rr - b * 240;
            ab[0] = A0 + (size_t)((b * 64 + t) * 240 + e) * 256;
            stp[0] = st0;
        } else {  // M_LN
            ab[0] = A0 + (size_t)((r >> 4) * 64 + tc + (r & 15)) * 256;
        }
    }
    const _Float16* wrow = W + (size_t)(o0 + srow) * K;

    f32x4 acc[4][4];
#pragma unroll
    for (int i = 0; i < 4; ++i)
#pragma unroll
        for (int j = 0; j < 4; ++j) acc[i][j] = (f32x4)0.f;

#pragma unroll
    for (int seg = 0; seg < NSEG; ++seg) {
        const _Float16* asrc = ab[seg];
        const float*    st   = stp[seg];
#pragma unroll 1
        for (int kk = 0; kk < 256; kk += 32) {
            f16x8 v0 = *(const f16x8*)(asrc + kk + scol);
            f16x8 v1 = *(const f16x8*)(asrc + kk + scol + 8);
            if constexpr (HAS_ST) {
#pragma unroll
                for (int j = 0; j < 8; ++j) {
                    int c0 = kk + scol + j, c1 = c0 + 8;
                    v0[j] = (_Float16)((float)v0[j] * st[512 + c0] + st[768 + c0]);
                    v1[j] = (_Float16)((float)v1[j] * st[512 + c1] + st[768 + c1]);
                }
            }
            f16x8 w0 = *(const f16x8*)(wrow + seg * 256 + kk + scol);
            f16x8 w1 = *(const f16x8*)(wrow + seg * 256 + kk + scol + 8);
            *(f16x8*)&As[srow][scol]     = v0;
            *(f16x8*)&As[srow][scol + 8] = v1;
            *(f16x8*)&Ws[srow][scol]     = w0;
            *(f16x8*)&Ws[srow][scol + 8] = w1;
            __syncthreads();

            f16x8 af[4], bf[4];
#pragma unroll
            for (int rf = 0; rf < 4; ++rf)
                af[rf] = *(const f16x8*)&As[wr * 64 + rf * 16 + lr][kg * 8];
#pragma unroll
            for (int cf = 0; cf < 4; ++cf)
                bf[cf] = *(const f16x8*)&Ws[wc * 64 + cf * 16 + lr][kg * 8];
#pragma unroll
            for (int rf = 0; rf < 4; ++rf)
#pragma unroll
                for (int cf = 0; cf < 4; ++cf)
                    acc[rf][cf] = __builtin_amdgcn_mfma_f32_16x16x32_f16(
                        af[rf], bf[cf], acc[rf][cf], 0, 0, 0);
            __syncthreads();
        }
    }

#pragma unroll
    for (int rf = 0; rf < 4; ++rf) {
#pragma unroll
        for (int cf = 0; cf < 4; ++cf) {
            int c = o0 + wc * 64 + cf * 16 + lr;
            float bv = bias ? bias[c] : 0.f;
#pragma unroll
            for (int rg = 0; rg < 4; ++rg) {
                int r = m0 + wr * 64 + rf * 16 + kg * 4 + rg;
                float v = acc[rf][cf][rg] + bv;
                if (DOELU) v = elu_f(v);
                out[(size_t)r * O + c] = (_Float16)v;
            }
        }
    }
}

// ---------------------------------------------------------------------------
// MLP1 first layer: K=4, direct.
// ---------------------------------------------------------------------------
__global__ void mlp1_g1(const float* __restrict__ inp, const float* __restrict__ w1,
                        const float* __restrict__ b1, _Float16* __restrict__ out)
{
    int idx = blockIdx.x * 256 + threadIdx.x;   // 8192 blocks
    int o = idx & 255, row = idx >> 8;
    int bt = row >> 4, n = row & 15, b = bt >> 6, t = bt & 63;
    const float* xp = inp + (((b * 16 + n) * 64 + t) << 2);
    const float* wp = w1 + (o << 2);
    float v = b1[o] + xp[0] * wp[0] + xp[1] * wp[1] + xp[2] * wp[2] + xp[3] * wp[3];
    out[idx] = (_Float16)elu_f(v);
}

__global__ void decode_k(const float* __restrict__ rel_rec, const float* __restrict__ rel_send,
                         int* __restrict__ sidx, int* __restrict__ ridx,
                         int* __restrict__ nodeEdges)
{
    int tid = threadIdx.x;
    if (tid < 240) {
        float as = 0.f, ar = 0.f;
        for (int n = 0; n < 16; ++n) {
            as += rel_send[tid * 16 + n] * (float)n;
            ar += rel_rec[tid * 16 + n] * (float)n;
        }
        sidx[tid] = (int)(as + 0.5f);
        ridx[tid] = (int)(ar + 0.5f);
    }
    __syncthreads();
    if (tid < 16) {
        int k = 0;
        for (int e = 0; e < 240; ++e)
            if (ridx[e] == tid) nodeEdges[tid * 15 + (k++)] = e;
    }
}

__global__ void cvt16(const float* __restrict__ src, _Float16* __restrict__ dst, int n)
{
    int i = blockIdx.x * 256 + threadIdx.x;
    if (i < n) dst[i] = (_Float16)src[i];
}

// ---------------------------------------------------------------------------
// BatchNorm stats (training mode, biased var).
// ---------------------------------------------------------------------------
__global__ void bn_stats(const _Float16* __restrict__ h, float* __restrict__ stats,
                         int Mrows, int rowsPerBlk)
{
    int col = threadIdx.x;
    int r0 = blockIdx.x * rowsPerBlk;
    int r1 = r0 + rowsPerBlk; if (r1 > Mrows) r1 = Mrows;
    float s = 0.f, q = 0.f;
    for (int r = r0; r < r1; ++r) {
        float v = (float)h[(size_t)r * 256 + col];
        s += v; q += v * v;
    }
    atomicAdd(&stats[col], s);
    atomicAdd(&stats[256 + col], q);
}

__global__ void bn_fin(float* __restrict__ stats, const float* __restrict__ g,
                       const float* __restrict__ be, float invM)
{
    int c = threadIdx.x;
    float m  = stats[c] * invM;
    float vr = stats[256 + c] * invM - m * m;
    float sc = rsqrtf(vr + 1e-5f) * g[c];
    stats[512 + c] = sc;
    stats[768 + c] = be[c] - m * sc;
}

// edge2node: (sum over 15 incoming edges of bn2(x2)) / 16
__global__ void e2n_k(const _Float16* __restrict__ x2, const float* __restrict__ st,
                      const int* __restrict__ nodeEdges, _Float16* __restrict__ out)
{
    int idx = blockIdx.x * 256 + threadIdx.x;   // 512*16*32
    int c = (idx & 31) * 8;
    int n = (idx >> 5) & 15;
    int bt = idx >> 9;
    float s[8] = {0, 0, 0, 0, 0, 0, 0, 0};
    for (int k = 0; k < 15; ++k) {
        int e = nodeEdges[n * 15 + k];
        f16x8 v = *(const f16x8*)&x2[(size_t)(bt * 240 + e) * 256 + c];
#pragma unroll
        for (int j = 0; j < 8; ++j) s[j] += (float)v[j];
    }
    f16x8 r;
#pragma unroll
    for (int j = 0; j < 8; ++j)
        r[j] = (_Float16)((st[512 + c + j] * s[j] + 15.f * st[768 + c + j]) * 0.0625f);
    *(f16x8*)&out[(size_t)(bt * 16 + n) * 256 + c] = r;
}

// ---------------------------------------------------------------------------
// LSTM 16-step chunk: 120 blocks x 16 rows. h fp16 in LDS, c f32 in regs;
// state carried across chunks in hstate/cstate.
// ---------------------------------------------------------------------------
__global__ __launch_bounds__(256) void lstm_seg(
    const _Float16* __restrict__ xw,    // [1920*16, 1024], row q = r*16+tt
    const _Float16* __restrict__ whh,   // [1024, 256]
    const float* __restrict__ bih, const float* __restrict__ bhh,
    _Float16* __restrict__ hout,        // [1920*64, 256], row r*64+t
    _Float16* __restrict__ hstate,      // [1920, 256]
    float* __restrict__ cstate,         // [1920, 256]
    int tc)
{
    __shared__ _Float16 hs[16][264];

    const int tid  = threadIdx.x;
    const int lane = tid & 63;
    const int w    = tid >> 6;
    const int lr   = lane & 15, kg = lane >> 4;
    const int row0 = blockIdx.x * 16;

    if (tc == 0) {
        for (int i = tid; i < 16 * 264; i += 256) (&hs[0][0])[i] = (_Float16)0.f;
    } else {
        for (int i = tid; i < 16 * 256; i += 256) {
            int r = i >> 8, c = i & 255;
            hs[r][c] = hstate[(size_t)(row0 + r) * 256 + c];
        }
    }

    float bsum[4][4];
#pragma unroll
    for (int g = 0; g < 4; ++g)
#pragma unroll
        for (int s = 0; s < 4; ++s) {
            int c = g * 256 + w * 64 + s * 16 + lr;
            bsum[g][s] = bih[c] + bhh[c];
        }

    float cst[4][4];
#pragma unroll
    for (int s = 0; s < 4; ++s)
#pragma unroll
        for (int rg = 0; rg < 4; ++rg)
            cst[s][rg] = (tc == 0) ? 0.f
                : cstate[(size_t)(row0 + kg * 4 + rg) * 256 + w * 64 + s * 16 + lr];
    __syncthreads();

    const size_t laneB = (size_t)(w * 64 + lr) * 256 + kg * 8;

#pragma unroll 1
    for (int tt = 0; tt < 16; ++tt) {
        f32x4 acc[4][4];
#pragma unroll
        for (int g = 0; g < 4; ++g)
#pragma unroll
            for (int s = 0; s < 4; ++s) acc[g][s] = (f32x4)0.f;

#pragma unroll
        for (int kc = 0; kc < 8; ++kc) {
            f16x8 af = *(const f16x8*)&hs[lr][kc * 32 + kg * 8];
#pragma unroll
            for (int g = 0; g < 4; ++g)
#pragma unroll
                for (int s = 0; s < 4; ++s) {
                    f16x8 bf = *(const f16x8*)(whh + laneB
                                + (size_t)(g * 256 + s * 16) * 256 + kc * 32);
                    acc[g][s] = __builtin_amdgcn_mfma_f32_16x16x32_f16(
                        af, bf, acc[g][s], 0, 0, 0);
                }
        }
        __syncthreads();   // done reading hs

#pragma unroll
        for (int s = 0; s < 4; ++s) {
            int col = w * 64 + s * 16 + lr;
#pragma unroll
            for (int rg = 0; rg < 4; ++rg) {
                int row = kg * 4 + rg;
                const _Float16* xp = xw + ((size_t)(row0 + row) * 16 + tt) * 1024 + col;
                float gi = acc[0][s][rg] + (float)xp[0]   + bsum[0][s];
                float gf = acc[1][s][rg] + (float)xp[256] + bsum[1][s];
                float gg = acc[2][s][rg] + (float)xp[512] + bsum[2][s];
                float go = acc[3][s][rg] + (float)xp[768] + bsum[3][s];
                float c  = sig_f(gf) * cst[s][rg] + sig_f(gi) * tanh_f(gg);
                cst[s][rg] = c;
                float h = sig_f(go) * tanh_f(c);
                hs[row][col] = (_Float16)h;
                hout[((size_t)(row0 + row) * 64 + tc + tt) * 256 + col] = (_Float16)h;
            }
        }
        __syncthreads();   // hs update visible
    }

#pragma unroll
    for (int s = 0; s < 4; ++s)
#pragma unroll
        for (int rg = 0; rg < 4; ++rg) {
            int row = kg * 4 + rg, col = w * 64 + s * 16 + lr;
            hstate[(size_t)(row0 + row) * 256 + col] = hs[row][col];
            cstate[(size_t)(row0 + row) * 256 + col] = cst[s][rg];
        }
}

// Final FC: out[r, 0:2] = h[r, t=63] @ fco_w^T + fco_b
__global__ void fco_k(const _Float16* __restrict__ hout, const float* __restrict__ w,
                      const float* __restrict__ b, float* __restrict__ out)
{
    int row = blockIdx.x;
    int lane = threadIdx.x;   // 64
    const _Float16* hp = hout + ((size_t)row * 64 + 63) * 256;
    float s0 = 0.f, s1 = 0.f;
    for (int k = lane; k < 256; k += 64) {
        float v = (float)hp[k];
        s0 += v * w[k];
        s1 += v * w[256 + k];
    }
#pragma unroll
    for (int off = 32; off; off >>= 1) {
        s0 += __shfl_down(s0, off, 64);
        s1 += __shfl_down(s1, off, 64);
    }
    if (lane == 0) {
        out[row * 2 + 0] = s0 + b[0];
        out[row * 2 + 1] = s1 + b[1];
    }
}

// ---------------------------------------------------------------------------
extern "C" void kernel_launch(void* const* d_in, const int* in_sizes, int n_in,
                              void* d_out, int out_size, void* d_ws, size_t ws_size,
                              hipStream_t stream)
{
    const float* inputs   = (const float*)d_in[0];
    const float* rel_rec  = (const float*)d_in[1];
    const float* rel_send = (const float*)d_in[2];
    const float *mw1[4], *mb1[4], *mw2[4], *mb2[4], *mg[4], *mbe[4];
    for (int i = 0; i < 4; ++i) {
        mw1[i] = (const float*)d_in[3 + 6 * i + 0];
        mb1[i] = (const float*)d_in[3 + 6 * i + 1];
        mw2[i] = (const float*)d_in[3 + 6 * i + 2];
        mb2[i] = (const float*)d_in[3 + 6 * i + 3];
        mg [i] = (const float*)d_in[3 + 6 * i + 4];
        mbe[i] = (const float*)d_in[3 + 6 * i + 5];
    }
    const float* lstm_wih = (const float*)d_in[27];
    const float* lstm_whh = (const float*)d_in[28];
    const float* lstm_bih = (const float*)d_in[29];
    const float* lstm_bhh = (const float*)d_in[30];
    const float* fco_w    = (const float*)d_in[31];
    const float* fco_b    = (const float*)d_in[32];
    float* out = (float*)d_out;
    (void)in_sizes; (void)n_in; (void)out_size; (void)ws_size;

    char* ws = (char*)d_ws;
    size_t off = 0;
    auto alloc = [&](size_t bytes) -> void* {
        void* p = ws + off;
        off = (off + bytes + 255) & ~(size_t)255;
        return p;
    };

    float* stats    = (float*)alloc(4 * 1024 * 4);   // 4 BN stat blocks
    int*   sidx     = (int*)alloc(240 * 4);
    int*   ridx     = (int*)alloc(240 * 4);
    int*   nodeEdges= (int*)alloc(240 * 4);

    const int wsz[7] = {65536, 131072, 65536, 65536, 65536, 196608, 65536};
    const float* wsrc[7] = {mw2[0], mw1[1], mw2[1], mw1[2], mw2[2], mw1[3], mw2[3]};
    _Float16* w16[7];
    for (int i = 0; i < 7; ++i) w16[i] = (_Float16*)alloc((size_t)wsz[i] * 2);
    _Float16* wih16 = (_Float16*)alloc((size_t)786432 * 2);  // all 3 layers
    _Float16* whh16 = (_Float16*)alloc((size_t)786432 * 2);

    const size_t SM = (size_t)8192 * 256;
    _Float16* h1    = (_Float16*)alloc(SM * 2);
    _Float16* h1b   = (_Float16*)alloc(SM * 2);
    _Float16* xn    = (_Float16*)alloc(SM * 2);
    _Float16* x3h   = (_Float16*)alloc(SM * 2);
    _Float16* x3raw = (_Float16*)alloc(SM * 2);
    _Float16* hstate= (_Float16*)alloc((size_t)1920 * 256 * 2);
    float*    cstate= (float*)alloc((size_t)1920 * 256 * 4);

    const size_t BIG = (size_t)122880 * 256;   // == 30720*1024
    _Float16* P = (_Float16*)alloc(BIG * 2);
    _Float16* Q = (_Float16*)alloc(BIG * 2);
    _Float16* R = (_Float16*)alloc(BIG * 2);

    float* st1 = stats, *st2 = stats + 1024, *st3 = stats + 2048, *st4 = stats + 3072;

    auto bn = [&](const _Float16* h, int Mrows, float* st, const float* g, const float* be) {
        hipMemsetAsync(st, 0, 512 * sizeof(float), stream);
        int nblk = (Mrows > 20000) ? 240 : 32;
        int rpb = (Mrows + nblk - 1) / nblk;
        bn_stats<<<nblk, 256, 0, stream>>>(h, st, Mrows, rpb);
        bn_fin<<<1, 256, 0, stream>>>(st, g, be, 1.f / (float)Mrows);
    };

    // --- setup ---
    decode_k<<<1, 256, 0, stream>>>(rel_rec, rel_send, sidx, ridx, nodeEdges);
    for (int i = 0; i < 7; ++i)
        cvt16<<<(wsz[i] + 255) / 256, 256, 0, stream>>>(wsrc[i], w16[i], wsz[i]);
    cvt16<<<3072, 256, 0, stream>>>(lstm_wih, wih16, 786432);
    cvt16<<<3072, 256, 0, stream>>>(lstm_whh, whh16, 786432);

    // --- MLP1 ---
    mlp1_g1<<<8192, 256, 0, stream>>>(inputs, mw1[0], mb1[0], h1);
    gemmg<M_ID, true><<<dim3(64, 2), 256, 0, stream>>>(
        h1, nullptr, nullptr, nullptr, sidx, ridx, w16[0], mb2[0], h1b, 8192, 256, 0);
    bn(h1b, 8192, st1, mg[0], mbe[0]);

    // --- MLP2 (node2edge gather + bn1 fused) ---
    gemmg<M_N2E, true><<<dim3(960, 2), 256, 0, stream>>>(
        h1b, nullptr, st1, nullptr, sidx, ridx, w16[1], mb1[1], P, 122880, 256, 0);
    gemmg<M_ID, true><<<dim3(960, 2), 256, 0, stream>>>(
        P, nullptr, nullptr, nullptr, sidx, ridx, w16[2], mb2[1], Q, 122880, 256, 0);
    bn(Q, 122880, st2, mg[1], mbe[1]);

    // --- edge2node (bn2 fused) + MLP3 ---
    e2n_k<<<1024, 256, 0, stream>>>(Q, st2, nodeEdges, xn);
    gemmg<M_ID, true><<<dim3(64, 2), 256, 0, stream>>>(
        xn, nullptr, nullptr, nullptr, sidx, ridx, w16[3], mb1[2], x3h, 8192, 256, 0);
    gemmg<M_ID, true><<<dim3(64, 2), 256, 0, stream>>>(
        x3h, nullptr, nullptr, nullptr, sidx, ridx, w16[4], mb2[2], x3raw, 8192, 256, 0);
    bn(x3raw, 8192, st3, mg[2], mbe[2]);

    // --- MLP4 (gather bn3(x3) + skip bn2(Q)) ---
    gemmg<M_M4, true><<<dim3(960, 2), 256, 0, stream>>>(
        x3raw, Q, st3, st2, sidx, ridx, w16[5], mb1[3], P, 122880, 256, 0);
    gemmg<M_ID, true><<<dim3(960, 2), 256, 0, stream>>>(
        P, nullptr, nullptr, nullptr, sidx, ridx, w16[6], mb2[3], Q, 122880, 256, 0);
    bn(Q, 122880, st4, mg[3], mbe[3]);

    // --- 3-layer LSTM, 16-step chunks; xw chunk buffer = P ---
    for (int l = 0; l < 3; ++l) {
        const _Float16* wih_l = wih16 + (size_t)l * 262144;
        const _Float16* whh_l = whh16 + (size_t)l * 262144;
        const float* bih_l = lstm_bih + l * 1024;
        const float* bhh_l = lstm_bhh + l * 1024;
        const _Float16* xsrc = (l == 0) ? Q : ((l == 1) ? R : Q);
        _Float16* hdst = (l == 1) ? Q : R;
        for (int c = 0; c < 4; ++c) {
            int tc = c * 16;
            if (l == 0)
                gemmg<M_L0, false><<<dim3(240, 8), 256, 0, stream>>>(
                    xsrc, nullptr, st4, nullptr, sidx, ridx, wih_l, nullptr,
                    P, 30720, 1024, tc);
            else
                gemmg<M_LN, false><<<dim3(240, 8), 256, 0, stream>>>(
                    xsrc, nullptr, nullptr, nullptr, sidx, ridx, wih_l, nullptr,
                    P, 30720, 1024, tc);
            lstm_seg<<<120, 256, 0, stream>>>(P, whh_l, bih_l, bhh_l,
                                              hdst, hstate, cstate, tc);
        }
    }

    // --- final FC (reads R = layer-2 h) ---
    fco_k<<<1920, 64, 0, stream>>>(R, fco_w, fco_b, out);
}